// Round 3
// baseline (495.043 us; speedup 1.0000x reference)
//
#include <hip/hip_runtime.h>

#define ROW_N 2048
#define ROW_K 1024   // zero the 1024 smallest per row

// Monotone map: float -> uint32 such that key order == float order (total order).
__device__ __forceinline__ unsigned f2key(float x) {
    unsigned u = __float_as_uint(x);
    // negative: flip all bits; positive: flip sign bit
    return u ^ ((unsigned)((int)u >> 31) | 0x80000000u);
}

__global__ __launch_bounds__(256)
void ktakes_kernel(const float* __restrict__ g, float* __restrict__ out) {
    const int row = blockIdx.x;
    const int tid = threadIdx.x;
    const int wave = tid >> 6;                 // 0..3
    const float* __restrict__ grow = g + (size_t)row * ROW_N;
    float* __restrict__ orow = out + (size_t)row * ROW_N;

    __shared__ unsigned hist4[4][256];         // per-wave privatized histograms
    __shared__ unsigned s_digit;
    __shared__ int s_rank;
    __shared__ int s_cnteq;
    __shared__ unsigned char s_flag[ROW_N];    // used only on the rare tie path

    // ---- load 8 elements/thread, coalesced float4s ----
    const float4* g4 = reinterpret_cast<const float4*>(grow);
    float4 va = g4[tid];
    float4 vb = g4[tid + 256];
    float xa[4] = {va.x, va.y, va.z, va.w};
    float xb[4] = {vb.x, vb.y, vb.z, vb.w};
    unsigned ka[4], kb[4];
#pragma unroll
    for (int c = 0; c < 4; ++c) { ka[c] = f2key(xa[c]); kb[c] = f2key(xb[c]); }

    // ---- radix select: find key at ascending rank (K-1) ----
    unsigned prefix = 0;
    int rank = ROW_K - 1;   // 1023

    for (int shift = 24; shift >= 0; shift -= 8) {
        // zero all 4 private histograms (1024 words, 4 per thread)
        unsigned* hflat = &hist4[0][0];
#pragma unroll
        for (int z = 0; z < 4; ++z) hflat[tid + 256 * z] = 0;
        __syncthreads();

        unsigned* h = hist4[wave];
        if (shift == 24) {
#pragma unroll
            for (int c = 0; c < 4; ++c) atomicAdd(&h[ka[c] >> 24], 1u);
#pragma unroll
            for (int c = 0; c < 4; ++c) atomicAdd(&h[kb[c] >> 24], 1u);
        } else {
            const unsigned hs = shift + 8;
#pragma unroll
            for (int c = 0; c < 4; ++c) {
                if (((ka[c] ^ prefix) >> hs) == 0)
                    atomicAdd(&h[(ka[c] >> shift) & 255u], 1u);
                if (((kb[c] ^ prefix) >> hs) == 0)
                    atomicAdd(&h[(kb[c] >> shift) & 255u], 1u);
            }
        }
        __syncthreads();

        // wave 0 scans the 256 bins (4 bins/lane + 64-lane shuffle scan)
        if (tid < 64) {
            unsigned b[4];
#pragma unroll
            for (int j = 0; j < 4; ++j)
                b[j] = hist4[0][tid * 4 + j] + hist4[1][tid * 4 + j] +
                       hist4[2][tid * 4 + j] + hist4[3][tid * 4 + j];
            unsigned s = b[0] + b[1] + b[2] + b[3];
            unsigned incl = s;
#pragma unroll
            for (int off = 1; off < 64; off <<= 1) {
                unsigned n = __shfl_up(incl, off, 64);
                if (tid >= off) incl += n;
            }
            unsigned excl = incl - s;
            int r = rank;
            if (r >= (int)excl && r < (int)incl) {
                int rr = r - (int)excl;
                unsigned d = tid * 4;
                if (rr >= (int)b[0]) { rr -= (int)b[0]; d++;
                    if (rr >= (int)b[1]) { rr -= (int)b[1]; d++;
                        if (rr >= (int)b[2]) { rr -= (int)b[2]; d++; } } }
                s_digit = d;
                s_rank = rr;
            }
        }
        __syncthreads();
        prefix |= (s_digit << shift);
        rank = s_rank;
    }

    const unsigned Kth = prefix;     // key at ascending rank 1023
    const int m = rank + 1;          // # of ==Kth elements to zero (lowest-index-first)

    // ---- count elements equal to Kth ----
    if (tid == 0) s_cnteq = 0;
    __syncthreads();
    int eqc = 0;
#pragma unroll
    for (int c = 0; c < 4; ++c) eqc += (ka[c] == Kth) + (kb[c] == Kth);
    if (eqc) atomicAdd(&s_cnteq, eqc);
    __syncthreads();

    const bool simple = (s_cnteq == m);  // all equals get zeroed (the ~always case)

    if (!simple) {
        // rare exact-tie path: mark first m equal-keys in global index order
        if (tid == 0) {
            int cnt = 0;
            for (int i = 0; i < ROW_N; ++i) {
                unsigned u = f2key(grow[i]);
                unsigned char f = 0;
                if (u == Kth && cnt < m) { f = 1; cnt++; }
                s_flag[i] = f;
            }
        }
        __syncthreads();
    }

    // ---- write output ----
    float4 oa, ob;
    float ra[4], rb[4];
#pragma unroll
    for (int c = 0; c < 4; ++c) {
        bool za, zb;
        if (simple) {
            za = (ka[c] <= Kth);
            zb = (kb[c] <= Kth);
        } else {
            za = (ka[c] < Kth) || (ka[c] == Kth && s_flag[4 * tid + c]);
            zb = (kb[c] < Kth) || (kb[c] == Kth && s_flag[1024 + 4 * tid + c]);
        }
        ra[c] = za ? 0.0f : xa[c];
        rb[c] = zb ? 0.0f : xb[c];
    }
    oa.x = ra[0]; oa.y = ra[1]; oa.z = ra[2]; oa.w = ra[3];
    ob.x = rb[0]; ob.y = rb[1]; ob.z = rb[2]; ob.w = rb[3];

    float4* o4 = reinterpret_cast<float4*>(orow);
    o4[tid] = oa;
    o4[tid + 256] = ob;
}

extern "C" void kernel_launch(void* const* d_in, const int* in_sizes, int n_in,
                              void* d_out, int out_size, void* d_ws, size_t ws_size,
                              hipStream_t stream) {
    const float* g = (const float*)d_in[0];
    float* out = (float*)d_out;
    const int rows = in_sizes[0] / ROW_N;   // 16 * 2048 = 32768
    hipLaunchKernelGGL(ktakes_kernel, dim3(rows), dim3(256), 0, stream, g, out);
}

// Round 5
// 433.000 us; speedup vs baseline: 1.1433x; 1.1433x over previous
//
#include <hip/hip_runtime.h>

#define ROW_N 2048
#define ROW_K 1024          // zero the 1024 smallest per row
#define NSUB 4              // sub-histograms per wave (lane & 3)
#define HPAD 264            // 256 bins + 8 pad -> sub s gets bank offset 8*s
#define WH   (NSUB * HPAD)  // 1056 dwords of histogram per wave
#define WSTRIDE (WH + 4)    // +4 dword stagger so waves' hot bins spread banks

// Wave-local LDS ordering: all 64 lanes' ds ops are in this wave's own stream;
// lgkmcnt(0) + "memory" clobber is a full fence for intra-wave LDS RAW/WAR.
__device__ __forceinline__ void wfence() {
    asm volatile("s_waitcnt lgkmcnt(0)" ::: "memory");
}

// Monotone bijection float -> uint32 (order-preserving, invertible).
__device__ __forceinline__ unsigned f2key(float x) {
    unsigned u = __float_as_uint(x);
    return u ^ ((unsigned)((int)u >> 31) | 0x80000000u);
}
__device__ __forceinline__ float key2f(unsigned k) {
    unsigned u = (k & 0x80000000u) ? (k ^ 0x80000000u) : ~k;
    return __uint_as_float(u);
}

__global__ __launch_bounds__(256)
void ktakes_kernel(const float* __restrict__ g, float* __restrict__ out) {
    const int tid  = threadIdx.x;
    const int wave = tid >> 6;
    const int lane = tid & 63;
    const int row  = blockIdx.x * 4 + wave;

    __shared__ unsigned H[4 * WSTRIDE];
    unsigned* hw   = H + wave * WSTRIDE;             // this wave's histograms
    unsigned* hsub = hw + (lane & (NSUB - 1)) * HPAD;

    const float4* g4 = reinterpret_cast<const float4*>(g + (size_t)row * ROW_N);
    float4*       o4 = reinterpret_cast<float4*>(out + (size_t)row * ROW_N);

    // ---- load full row into this wave: 32 keys/lane, coalesced float4 ----
    unsigned k[32];
#pragma unroll
    for (int j = 0; j < 8; ++j) {
        float4 v = g4[j * 64 + lane];               // element idx 256j + 4*lane + c
        k[4*j+0] = f2key(v.x); k[4*j+1] = f2key(v.y);
        k[4*j+2] = f2key(v.z); k[4*j+3] = f2key(v.w);
    }

    // ---- radix select rank (K-1), 4 rounds of 8 bits, wave-synchronous ----
    unsigned prefix = 0;
    int rank = ROW_K - 1;                           // 1023
    int cnteq = 0;

#pragma unroll
    for (int r = 0; r < 4; ++r) {
        const int shift = 24 - 8 * r;

        // zero this wave's 1056 histogram words
#pragma unroll
        for (int i = 0; i < 17; ++i) {
            int idx = i * 64 + lane;
            if (idx < WH) hw[idx] = 0;
        }
        wfence();

        // count into lane&3's sub-histogram
        if (r == 0) {
#pragma unroll
            for (int c = 0; c < 32; ++c)
                atomicAdd(&hsub[k[c] >> 24], 1u);
        } else {
            const int hs = shift + 8;
#pragma unroll
            for (int c = 0; c < 32; ++c)
                if (((k[c] ^ prefix) >> hs) == 0)
                    atomicAdd(&hsub[(k[c] >> shift) & 255u], 1u);
        }
        wfence();

        // all-lane scan: lane handles bins 4*lane .. 4*lane+3
        uint4 h0 = *reinterpret_cast<const uint4*>(&hw[0 * HPAD + 4 * lane]);
        uint4 h1 = *reinterpret_cast<const uint4*>(&hw[1 * HPAD + 4 * lane]);
        uint4 h2 = *reinterpret_cast<const uint4*>(&hw[2 * HPAD + 4 * lane]);
        uint4 h3 = *reinterpret_cast<const uint4*>(&hw[3 * HPAD + 4 * lane]);
        unsigned b0 = h0.x + h1.x + h2.x + h3.x;
        unsigned b1 = h0.y + h1.y + h2.y + h3.y;
        unsigned b2 = h0.z + h1.z + h2.z + h3.z;
        unsigned b3 = h0.w + h1.w + h2.w + h3.w;
        wfence();   // reads drained before next round's zeroing

        unsigned s4 = b0 + b1 + b2 + b3;
        unsigned incl = s4;
#pragma unroll
        for (int off = 1; off < 64; off <<= 1) {
            unsigned n = __shfl_up(incl, off, 64);
            if (lane >= off) incl += n;
        }
        int excl = (int)(incl - s4);
        bool found = (rank >= excl) && (rank < (int)incl);

        // per-lane candidate digit / remaining-rank / bin-count (no array indexing)
        int rr = rank - excl;
        unsigned d = 4 * lane;
        unsigned beq = b0;
        if (found) {
            if (rr >= (int)b0) { rr -= (int)b0; d++; beq = b1;
                if (rr >= (int)b1) { rr -= (int)b1; d++; beq = b2;
                    if (rr >= (int)b2) { rr -= (int)b2; d++; beq = b3; } } }
        }
        unsigned long long bal = __ballot(found);
        int src = __builtin_ctzll(bal);             // exactly one lane found
        d     = (unsigned)__shfl((int)d, src, 64);
        rr    = __shfl(rr, src, 64);
        beq   = (unsigned)__shfl((int)beq, src, 64);

        prefix |= d << shift;
        rank  = rr;
        cnteq = (int)beq;
    }

    const unsigned Kth = prefix;    // key at ascending rank 1023
    const int m = rank + 1;         // # of ==Kth elems to zero (lowest index first)

    // ---- build zero-mask (bit c == zero element k[c]) ----
    unsigned zm = 0;
    if (cnteq == m) {
        // all boundary-key duplicates get zeroed: k <= Kth
#pragma unroll
        for (int c = 0; c < 32; ++c)
            if (k[c] <= Kth) zm |= 1u << c;
    } else {
        // rare tie path: zero only first m equals in global index order
        int base = 0;
#pragma unroll
        for (int j = 0; j < 8; ++j) {
            int eqmask = 0, e = 0;
#pragma unroll
            for (int c = 0; c < 4; ++c) {
                bool q = (k[4*j+c] == Kth);
                eqmask |= (int)q << c; e += (int)q;
            }
            int incl = e;
#pragma unroll
            for (int off = 1; off < 64; off <<= 1) {
                int n = __shfl_up(incl, off, 64);
                if (lane >= off) incl += n;
            }
            int excl = incl - e;
            int tot = __shfl(incl, 63, 64);
            int pos = base + excl;                 // index order = (j, lane, c)
#pragma unroll
            for (int c = 0; c < 4; ++c) {
                if (eqmask & (1 << c)) {
                    if (pos < m) zm |= 1u << (4*j+c);
                    pos++;
                }
            }
            base += tot;
        }
#pragma unroll
        for (int c = 0; c < 32; ++c)
            if (k[c] < Kth) zm |= 1u << c;
    }

    // ---- write output (reconstruct floats from keys) ----
#pragma unroll
    for (int j = 0; j < 8; ++j) {
        float4 v;
        v.x = (zm >> (4*j+0)) & 1u ? 0.0f : key2f(k[4*j+0]);
        v.y = (zm >> (4*j+1)) & 1u ? 0.0f : key2f(k[4*j+1]);
        v.z = (zm >> (4*j+2)) & 1u ? 0.0f : key2f(k[4*j+2]);
        v.w = (zm >> (4*j+3)) & 1u ? 0.0f : key2f(k[4*j+3]);
        o4[j * 64 + lane] = v;
    }
}

extern "C" void kernel_launch(void* const* d_in, const int* in_sizes, int n_in,
                              void* d_out, int out_size, void* d_ws, size_t ws_size,
                              hipStream_t stream) {
    const float* g = (const float*)d_in[0];
    float* out = (float*)d_out;
    const int rows = in_sizes[0] / ROW_N;     // 32768, divisible by 4
    hipLaunchKernelGGL(ktakes_kernel, dim3(rows / 4), dim3(256), 0, stream, g, out);
}